// Round 3
// baseline (239.631 us; speedup 1.0000x reference)
//
#include <hip/hip_runtime.h>
#include <stdint.h>

// B=32, C=256, H=W=32 (HW=1024), GROUPS=32, EPS=1e-5.
// K0 wprep : Wt[d][c] = gs[c]*W[c][d]*scale (bf16); bias[d]=(b[d]+sum_c gb[c]W[c][d])*scale
//            q-scale = log2(e)/16  (folds softmax 1/sqrt(C) AND exp->exp2 domain)
// K1 gn    : Xh[b][p][c] = (x-mu)*rsqrt(var+eps) (bf16)
// K2 gemmNT: shared B-tile staged via global_load_lds, XOR-swizzled
// K3 attn<NH>: flash attn, KV-split NH ways (grid 1024 @ NH=2 -> 3 blocks/CU),
//            defer-max (skip O-rescale when tile max stable), setprio on MFMA
// K3b merge: combine the two KV-halves (in-place into O0)
// K4 gemmNT: out = x + Wo^T O + bo (fp32)

#define NB 32
#define CH 256
#define HWPX 1024

typedef __bf16 bf16x8 __attribute__((ext_vector_type(8)));
typedef float f32x4 __attribute__((ext_vector_type(4)));
typedef unsigned short u16;
typedef u16 u16x8 __attribute__((ext_vector_type(8)));

__device__ __forceinline__ u16 f2bf(float f) {
    union { float f; unsigned int u; } v; v.f = f;
    unsigned int r = v.u + 0x7FFFu + ((v.u >> 16) & 1u);
    return (u16)(r >> 16);
}
__device__ __forceinline__ float bf2f(u16 u) {
    union { unsigned int u; float f; } v; v.u = ((unsigned int)u) << 16;
    return v.f;
}
__device__ __forceinline__ bf16x8 ldb8(const u16* p) {
    return __builtin_bit_cast(bf16x8, *(const u16x8*)p);
}
__device__ __forceinline__ void gld_lds16(const u16* g, u16* l) {
    __builtin_amdgcn_global_load_lds(
        (const __attribute__((address_space(1))) void*)g,
        (__attribute__((address_space(3))) void*)l, 16, 0, 0);
}

// ---------------- K0: weight prep ----------------
__global__ __launch_bounds__(256) void wprep(
    const float* __restrict__ Wq, const float* __restrict__ bq,
    const float* __restrict__ gqs, const float* __restrict__ gqb,
    const float* __restrict__ Wk, const float* __restrict__ bk,
    const float* __restrict__ gks, const float* __restrict__ gkb,
    const float* __restrict__ Wv, const float* __restrict__ bv,
    const float* __restrict__ gvs, const float* __restrict__ gvb,
    const float* __restrict__ Wo, const float* __restrict__ bo,
    u16* __restrict__ Wt, float* __restrict__ bias)
{
    int m = blockIdx.x >> 8;
    int d = blockIdx.x & 255;
    int c = threadIdx.x;
    const float *W, *bb, *gs, *gb; float scale;
    const float QSC = 0.09016844005556021f;   // log2(e)/16
    if (m == 0)      { W = Wq; bb = bq; gs = gqs; gb = gqb; scale = QSC; }
    else if (m == 1) { W = Wk; bb = bk; gs = gks; gb = gkb; scale = 1.f; }
    else if (m == 2) { W = Wv; bb = bv; gs = gvs; gb = gvb; scale = 1.f; }
    else             { W = Wo; bb = bo; gs = nullptr; gb = nullptr; scale = 1.f; }
    float w   = W[c * 256 + d];
    float gsc = gs ? gs[c] : 1.f;
    float gbc = gb ? gb[c] : 0.f;
    Wt[((size_t)m << 16) + d * 256 + c] = f2bf(w * gsc * scale);
    __shared__ float red[256];
    red[c] = gbc * w;
    __syncthreads();
    for (int s = 128; s > 0; s >>= 1) { if (c < s) red[c] += red[c + s]; __syncthreads(); }
    if (c == 0) bias[m * 256 + d] = (bb[d] + red[0]) * scale;
}

// ---------------- K1: groupnorm ----------------
__global__ __launch_bounds__(256) void gn_kernel(const float* __restrict__ x,
                                                 u16* __restrict__ Xh)
{
    int blk = blockIdx.x;
    int b = blk >> 5, g = blk & 31;
    const float* base = x + (size_t)(b * 256 + g * 8) * 1024;
    int t = threadIdx.x;
    float s = 0.f, s2 = 0.f;
    for (int i = 0; i < 32; i++) { float v = base[t + i * 256]; s += v; s2 += v * v; }
    __shared__ float rs[256], rq[256];
    rs[t] = s; rq[t] = s2;
    __syncthreads();
    for (int k = 128; k > 0; k >>= 1) {
        if (t < k) { rs[t] += rs[t + k]; rq[t] += rq[t + k]; }
        __syncthreads();
    }
    float mu  = rs[0] * (1.f / 8192.f);
    float var = rq[0] * (1.f / 8192.f) - mu * mu;
    float rv  = rsqrtf(var + 1e-5f);
    u16* outp = Xh + (size_t)b * (HWPX * CH) + g * 8;
    for (int it = 0; it < 4; it++) {
        int p = t + it * 256;
        u16x8 tv;
        #pragma unroll
        for (int c2 = 0; c2 < 8; c2++) tv[c2] = f2bf((base[c2 * 1024 + p] - mu) * rv);
        *(u16x8*)(outp + (size_t)p * 256) = tv;
    }
}

// ---------------- K2/K4: NT GEMM, shared B-tile in LDS ----------------
template <int MODE>
__global__ __launch_bounds__(256) void gemm_nt(
    const u16* __restrict__ A, const u16* __restrict__ Bm,
    const float* __restrict__ bias,
    u16* __restrict__ Cb, float* __restrict__ Cf,
    const float* __restrict__ xres)
{
    __shared__ __align__(16) u16 Bt[64 * 256];
    int tid = threadIdx.x;
    int lane = tid & 63, wave = tid >> 6;
    int m0 = blockIdx.y * 64 + wave * 16;
    int n0 = blockIdx.x * 64;

    #pragma unroll
    for (int i = 0; i < 8; i++) {
        int G = i * 256 + tid;
        int row = G >> 5, g = G & 31;
        const u16* src = Bm + (size_t)(n0 + row) * 256 + ((g ^ (row & 7)) << 3);
        gld_lds16(src, Bt + (size_t)(i * 256 + wave * 64) * 8);
    }

    int lr = lane & 15, hk = lane >> 4, lk = hk * 8;
    int ksw = lr & 7;
    const u16* Ap = A + (size_t)(m0 + lr) * 256 + lk;
    bf16x8 af[8];
    #pragma unroll
    for (int kk = 0; kk < 8; kk++) af[kk] = ldb8(Ap + kk * 32);

    __syncthreads();

    f32x4 acc[4] = {};
    #pragma unroll
    for (int kk = 0; kk < 8; kk++) {
        #pragma unroll
        for (int nt = 0; nt < 4; nt++) {
            int row = nt * 16 + lr;
            int g = (kk * 4 + hk) ^ ksw;
            bf16x8 bf = ldb8(Bt + (size_t)(row * 32 + g) * 8);
            acc[nt] = __builtin_amdgcn_mfma_f32_16x16x32_bf16(af[kk], bf, acc[nt], 0, 0, 0);
        }
    }
    int rbase = m0 + (hk << 2);
    #pragma unroll
    for (int nt = 0; nt < 4; nt++) {
        int col = n0 + nt * 16 + lr;
        #pragma unroll
        for (int j = 0; j < 4; j++) {
            int row = rbase + j;
            float v = acc[nt][j];
            if (MODE == 0) {
                v += bias[col];
                Cb[(size_t)row * 256 + col] = f2bf(v);
            } else {
                int b = col >> 10, p = col & 1023;
                size_t off = (size_t)b * (CH * HWPX) + (size_t)row * 1024 + p;
                v += bias[row];
                if (MODE == 1) Cb[off] = f2bf(v);
                else           Cf[off] = v + xres[off];
            }
        }
    }
}

// ---------------- K3: flash attention, KV-split + defer-max ----------------
// NH=2: grid 1024 (b,qb,half), 16 KV steps each; NH=1: grid 512, 32 steps.
template <int NH>
__global__ __launch_bounds__(256) void attn(
    const u16* __restrict__ Qt, const u16* __restrict__ Kt,
    const u16* __restrict__ Vc, u16* __restrict__ O0,
    u16* __restrict__ O1, float* __restrict__ ML)
{
    __shared__ __align__(16) u16 Kbuf[2][32 * 256];   // 2 x 16 KB
    __shared__ __align__(16) u16 Vbuf[256 * 32];      // 16 KB
    __shared__ __align__(16) u16 Pbuf[4][16 * 40];    // 5 KB

    int tid = threadIdx.x;
    int lane = tid & 63, wave = tid >> 6;
    int bid = blockIdx.x;
    int b, qb, h;
    if (NH == 2) {
        // bijective: XCD x gets batches x*4..x*4+3, all 32 blocks of a batch co-located
        int x = bid & 7, r = bid >> 3;
        b = x * 4 + (r & 3);
        int r2 = r >> 2;
        qb = r2 & 15;
        h  = r2 >> 4;
    } else {
        b = (bid & 7) + ((bid >> 7) << 3);
        qb = (bid >> 3) & 15;
        h = 0;
    }
    const int NSTEP = (1024 / NH) / 32;

    const u16* Qb = Qt + (size_t)b * (HWPX * CH);
    const u16* Kb = Kt + (size_t)b * (HWPX * CH) + (size_t)h * 512 * 256;
    const u16* Vb = Vc + (size_t)b * (CH * HWPX) + (size_t)h * 512;
    int q0 = qb * 64 + wave * 16;
    int lr = lane & 15, hk = lane >> 4, lk = hk * 8;
    int ksw = lr & 7;

    int koff[4], voff[4];
    #pragma unroll
    for (int i = 0; i < 4; i++) {
        int G = i * 256 + tid;
        int kr = G >> 5, kg = G & 31;
        koff[i] = kr * 256 + ((kg ^ (kr & 7)) << 3);
        int vr = G >> 2, vg = G & 3;
        voff[i] = vr * 1024 + ((vg ^ ((vr >> 1) & 3)) << 3);
    }

    bf16x8 qf[8];
    #pragma unroll
    for (int kk = 0; kk < 8; kk++)
        qf[kk] = ldb8(Qb + (size_t)(q0 + lr) * 256 + kk * 32 + lk);

    f32x4 oa[16] = {};
    float m_run[4] = {-1e30f, -1e30f, -1e30f, -1e30f};
    float l_run[4] = {0.f, 0.f, 0.f, 0.f};
    u16* Pw = Pbuf[wave];

    #pragma unroll
    for (int i = 0; i < 4; i++)
        gld_lds16(Kb + koff[i], Kbuf[0] + (size_t)(i * 256 + wave * 64) * 8);

    for (int t = 0; t < NSTEP; ++t) {
        int kcur = t & 1;
        __syncthreads();   // B1: K(t) staged; Vbuf/P of t-1 consumed

        if (t < NSTEP - 1) {
            u16* kd = Kbuf[0] + (size_t)(kcur ^ 1) * (32 * 256);
            const u16* ks = Kb + (t + 1) * (32 * 256);
            #pragma unroll
            for (int i = 0; i < 4; i++)
                gld_lds16(ks + koff[i], kd + (size_t)(i * 256 + wave * 64) * 8);
        }
        {
            const u16* vs = Vb + t * 32;
            #pragma unroll
            for (int i = 0; i < 4; i++)
                gld_lds16(vs + voff[i], Vbuf + (size_t)(i * 256 + wave * 64) * 8);
        }

        // ---- QK^T (log2 domain) ----
        const u16* krd = Kbuf[0] + (size_t)kcur * (32 * 256);
        f32x4 sacc[2] = {};
        __builtin_amdgcn_s_setprio(1);
        #pragma unroll
        for (int kk = 0; kk < 8; kk++) {
            #pragma unroll
            for (int nt = 0; nt < 2; nt++) {
                int row = nt * 16 + lr;
                int g = (kk * 4 + hk) ^ ksw;
                bf16x8 kf = ldb8(krd + (size_t)(row * 32 + g) * 8);
                sacc[nt] = __builtin_amdgcn_mfma_f32_16x16x32_bf16(qf[kk], kf, sacc[nt], 0, 0, 0);
            }
        }
        __builtin_amdgcn_s_setprio(0);

        // ---- online softmax with defer-max (THR=4 -> p <= 16, bf16-safe) ----
        float mx[4];
        #pragma unroll
        for (int j = 0; j < 4; j++) {
            float m2 = fmaxf(sacc[0][j], sacc[1][j]);
            #pragma unroll
            for (int d2 = 1; d2 < 16; d2 <<= 1) m2 = fmaxf(m2, __shfl_xor(m2, d2));
            mx[j] = m2;
        }
        bool stable = (mx[0] - m_run[0] <= 4.f) && (mx[1] - m_run[1] <= 4.f) &&
                      (mx[2] - m_run[2] <= 4.f) && (mx[3] - m_run[3] <= 4.f);
        if (!__all(stable)) {
            float sc[4];
            #pragma unroll
            for (int j = 0; j < 4; j++) {
                float mn = fmaxf(m_run[j], mx[j]);
                sc[j] = exp2f(m_run[j] - mn);
                m_run[j] = mn;
                l_run[j] *= sc[j];
            }
            #pragma unroll
            for (int ct = 0; ct < 16; ct++) {
                f32x4 tacc = oa[ct];
                tacc[0] *= sc[0]; tacc[1] *= sc[1]; tacc[2] *= sc[2]; tacc[3] *= sc[3];
                oa[ct] = tacc;
            }
        }
        #pragma unroll
        for (int j = 0; j < 4; j++) {
            float p0 = exp2f(sacc[0][j] - m_run[j]);
            float p1 = exp2f(sacc[1][j] - m_run[j]);
            float rsum = p0 + p1;
            #pragma unroll
            for (int d2 = 1; d2 < 16; d2 <<= 1) rsum += __shfl_xor(rsum, d2);
            l_run[j] += rsum;
            Pw[(hk * 4 + j) * 40 + lr]      = f2bf(p0);
            Pw[(hk * 4 + j) * 40 + 16 + lr] = f2bf(p1);
        }

        __syncthreads();   // B2: V(t)+K(t+1) staged; P visible

        // ---- PV ----
        bf16x8 pf = ldb8(Pw + lr * 40 + lk);
        int vsw = (lr >> 1) & 3;
        __builtin_amdgcn_s_setprio(1);
        #pragma unroll
        for (int ct = 0; ct < 16; ct++) {
            int row = ct * 16 + lr;
            int vg = hk ^ vsw;
            bf16x8 vf = ldb8(Vbuf + (size_t)(row * 4 + vg) * 8);
            oa[ct] = __builtin_amdgcn_mfma_f32_16x16x32_bf16(pf, vf, oa[ct], 0, 0, 0);
        }
        __builtin_amdgcn_s_setprio(0);
    }

    float rinv[4];
    #pragma unroll
    for (int j = 0; j < 4; j++) rinv[j] = 1.f / l_run[j];
    u16* Ob = ((NH == 2 && h == 1) ? O1 : O0) + (size_t)b * (HWPX * CH);
    #pragma unroll
    for (int ct = 0; ct < 16; ct++) {
        #pragma unroll
        for (int j = 0; j < 4; j++) {
            Ob[(size_t)(q0 + hk * 4 + j) * 256 + ct * 16 + lr] = f2bf(oa[ct][j] * rinv[j]);
        }
    }
    if (NH == 2 && lr == 0) {
        #pragma unroll
        for (int j = 0; j < 4; j++) {
            int qrow = q0 + hk * 4 + j;
            size_t idx = ((size_t)h * 32768 + (size_t)b * 1024 + qrow) * 2;
            ML[idx] = m_run[j];
            ML[idx + 1] = l_run[j];
        }
    }
}

// ---------------- K3b: merge the two KV-halves (in place into O0) ----------------
__global__ __launch_bounds__(256) void merge_halves(
    u16* __restrict__ O0, const u16* __restrict__ O1, const float* __restrict__ ML)
{
    int gid = blockIdx.x * 256 + threadIdx.x;   // 32 threads per row
    int row = gid >> 5;
    int c8  = (gid & 31) << 3;
    float m0 = ML[row * 2], l0 = ML[row * 2 + 1];
    float m1 = ML[(32768 + row) * 2], l1 = ML[(32768 + row) * 2 + 1];
    float m  = fmaxf(m0, m1);
    float w0 = l0 * exp2f(m0 - m), w1 = l1 * exp2f(m1 - m);
    float inv = 1.f / (w0 + w1);
    w0 *= inv; w1 *= inv;
    u16* p0 = O0 + (size_t)row * 256 + c8;
    const u16* p1 = O1 + (size_t)row * 256 + c8;
    u16x8 a = *(const u16x8*)p0;
    u16x8 c = *(const u16x8*)p1;
    u16x8 r;
    #pragma unroll
    for (int i = 0; i < 8; i++) r[i] = f2bf(w0 * bf2f(a[i]) + w1 * bf2f(c[i]));
    *(u16x8*)p0 = r;
}

// ---------------- host launch ----------------
extern "C" void kernel_launch(void* const* d_in, const int* in_sizes, int n_in,
                              void* d_out, int out_size, void* d_ws, size_t ws_size,
                              hipStream_t stream)
{
    const float* x   = (const float*)d_in[0];
    const float* Wq  = (const float*)d_in[1];
    const float* bq  = (const float*)d_in[2];
    const float* Wk  = (const float*)d_in[3];
    const float* bk  = (const float*)d_in[4];
    const float* Wv  = (const float*)d_in[5];
    const float* bv  = (const float*)d_in[6];
    const float* Wo  = (const float*)d_in[7];
    const float* bo  = (const float*)d_in[8];
    const float* gqs = (const float*)d_in[9];
    const float* gqb = (const float*)d_in[10];
    const float* gks = (const float*)d_in[11];
    const float* gkb = (const float*)d_in[12];
    const float* gvs = (const float*)d_in[13];
    const float* gvb = (const float*)d_in[14];

    const size_t BIGB = (size_t)NB * HWPX * CH * 2;          // 16 MB per bf16 buffer
    const size_t WTB  = 4 * 65536 * 2;                       // 512 KB
    const size_t BIASB = 4 * 256 * 4;                        // 4 KB
    const size_t MLB  = 2 * 32768 * 2 * 4;                   // 512 KB
    size_t need_base  = 4 * BIGB + WTB + BIASB;
    size_t need_split = need_base + BIGB + MLB;
    if (ws_size < need_base) return;

    char* w = (char*)d_ws;
    u16*  Xh   = (u16*)(w);                    // [B][p][c]; O-half0 after V proj
    u16*  Qt   = (u16*)(w + BIGB);
    u16*  Kt   = (u16*)(w + 2 * BIGB);
    u16*  Vc   = (u16*)(w + 3 * BIGB);
    u16*  Wt   = (u16*)(w + 4 * BIGB);
    float* bias = (float*)(w + 4 * BIGB + WTB);
    u16*  O1   = (u16*)(w + 4 * BIGB + WTB + BIASB);
    float* ML  = (float*)(w + 4 * BIGB + WTB + BIASB + BIGB);

    wprep<<<dim3(1024), dim3(256), 0, stream>>>(Wq, bq, gqs, gqb, Wk, bk, gks, gkb,
                                                Wv, bv, gvs, gvb, Wo, bo, Wt, bias);
    gn_kernel<<<dim3(1024), dim3(256), 0, stream>>>(x, Xh);

    gemm_nt<0><<<dim3(4, 512), dim3(256), 0, stream>>>(Xh, Wt,           bias,       Qt, nullptr, nullptr);
    gemm_nt<0><<<dim3(4, 512), dim3(256), 0, stream>>>(Xh, Wt + 65536,   bias + 256, Kt, nullptr, nullptr);
    gemm_nt<1><<<dim3(512, 4), dim3(256), 0, stream>>>(Wt + 131072, Xh,  bias + 512, Vc, nullptr, nullptr);

    if (ws_size >= need_split) {
        attn<2><<<dim3(1024), dim3(256), 0, stream>>>(Qt, Kt, Vc, Xh, O1, ML);
        merge_halves<<<dim3(4096), dim3(256), 0, stream>>>(Xh, O1, ML);
    } else {
        attn<1><<<dim3(512), dim3(256), 0, stream>>>(Qt, Kt, Vc, Xh, nullptr, nullptr);
    }

    gemm_nt<2><<<dim3(512, 4), dim3(256), 0, stream>>>(Wt + 196608, Xh,  bias + 768, nullptr, (float*)d_out, x);
}

// Round 4
// 219.895 us; speedup vs baseline: 1.0898x; 1.0898x over previous
//
#include <hip/hip_runtime.h>
#include <stdint.h>

// B=32, C=256, H=W=32 (HW=1024), GROUPS=32, EPS=1e-5.
// K0 wprep : Wt[d][c] = gs[c]*W[c][d]*scale (bf16); bias[d]=(b[d]+sum_c gb[c]W[c][d])*scale
//            q-scale = log2(e)/16  (folds softmax 1/sqrt(C) AND exp->exp2 domain)
// K1 gn    : Xh[b][p][c] = (x-mu)*rsqrt(var+eps) (bf16)
// K2 gemmNT: shared B-tile staged via global_load_lds, XOR-swizzled
// K3 attn<2>: flash attn, KV-split x2, grid 1024, LDS 52KB exact (3 blocks/CU),
//            shuffle-free defer-max softmax (lane-local, __all-gated), lane-partial l,
//            NO setprio, XCD-gathered block mapping
// K3b merge: combine the two KV-halves (in-place into O0)
// K4 gemmNT: out = x + Wo^T O + bo (fp32)

#define NB 32
#define CH 256
#define HWPX 1024

typedef __bf16 bf16x8 __attribute__((ext_vector_type(8)));
typedef float f32x4 __attribute__((ext_vector_type(4)));
typedef unsigned short u16;
typedef u16 u16x8 __attribute__((ext_vector_type(8)));

__device__ __forceinline__ u16 f2bf(float f) {
    __bf16 h = (__bf16)f;                       // native RNE cvt (v_cvt_pk_bf16_f32)
    return __builtin_bit_cast(u16, h);
}
__device__ __forceinline__ float bf2f(u16 u) {
    union { unsigned int u; float f; } v; v.u = ((unsigned int)u) << 16;
    return v.f;
}
__device__ __forceinline__ bf16x8 ldb8(const u16* p) {
    return __builtin_bit_cast(bf16x8, *(const u16x8*)p);
}
__device__ __forceinline__ void gld_lds16(const u16* g, u16* l) {
    __builtin_amdgcn_global_load_lds(
        (const __attribute__((address_space(1))) void*)g,
        (__attribute__((address_space(3))) void*)l, 16, 0, 0);
}

// ---------------- K0: weight prep ----------------
__global__ __launch_bounds__(256) void wprep(
    const float* __restrict__ Wq, const float* __restrict__ bq,
    const float* __restrict__ gqs, const float* __restrict__ gqb,
    const float* __restrict__ Wk, const float* __restrict__ bk,
    const float* __restrict__ gks, const float* __restrict__ gkb,
    const float* __restrict__ Wv, const float* __restrict__ bv,
    const float* __restrict__ gvs, const float* __restrict__ gvb,
    const float* __restrict__ Wo, const float* __restrict__ bo,
    u16* __restrict__ Wt, float* __restrict__ bias)
{
    int m = blockIdx.x >> 8;
    int d = blockIdx.x & 255;
    int c = threadIdx.x;
    const float *W, *bb, *gs, *gb; float scale;
    const float QSC = 0.09016844005556021f;   // log2(e)/16
    if (m == 0)      { W = Wq; bb = bq; gs = gqs; gb = gqb; scale = QSC; }
    else if (m == 1) { W = Wk; bb = bk; gs = gks; gb = gkb; scale = 1.f; }
    else if (m == 2) { W = Wv; bb = bv; gs = gvs; gb = gvb; scale = 1.f; }
    else             { W = Wo; bb = bo; gs = nullptr; gb = nullptr; scale = 1.f; }
    float w   = W[c * 256 + d];
    float gsc = gs ? gs[c] : 1.f;
    float gbc = gb ? gb[c] : 0.f;
    Wt[((size_t)m << 16) + d * 256 + c] = f2bf(w * gsc * scale);
    __shared__ float red[256];
    red[c] = gbc * w;
    __syncthreads();
    for (int s = 128; s > 0; s >>= 1) { if (c < s) red[c] += red[c + s]; __syncthreads(); }
    if (c == 0) bias[m * 256 + d] = (bb[d] + red[0]) * scale;
}

// ---------------- K1: groupnorm ----------------
__global__ __launch_bounds__(256) void gn_kernel(const float* __restrict__ x,
                                                 u16* __restrict__ Xh)
{
    int blk = blockIdx.x;
    int b = blk >> 5, g = blk & 31;
    const float* base = x + (size_t)(b * 256 + g * 8) * 1024;
    int t = threadIdx.x;
    float s = 0.f, s2 = 0.f;
    for (int i = 0; i < 32; i++) { float v = base[t + i * 256]; s += v; s2 += v * v; }
    __shared__ float rs[256], rq[256];
    rs[t] = s; rq[t] = s2;
    __syncthreads();
    for (int k = 128; k > 0; k >>= 1) {
        if (t < k) { rs[t] += rs[t + k]; rq[t] += rq[t + k]; }
        __syncthreads();
    }
    float mu  = rs[0] * (1.f / 8192.f);
    float var = rq[0] * (1.f / 8192.f) - mu * mu;
    float rv  = rsqrtf(var + 1e-5f);
    u16* outp = Xh + (size_t)b * (HWPX * CH) + g * 8;
    for (int it = 0; it < 4; it++) {
        int p = t + it * 256;
        u16x8 tv;
        #pragma unroll
        for (int c2 = 0; c2 < 8; c2++) tv[c2] = f2bf((base[c2 * 1024 + p] - mu) * rv);
        *(u16x8*)(outp + (size_t)p * 256) = tv;
    }
}

// ---------------- K2/K4: NT GEMM, shared B-tile in LDS ----------------
template <int MODE>
__global__ __launch_bounds__(256) void gemm_nt(
    const u16* __restrict__ A, const u16* __restrict__ Bm,
    const float* __restrict__ bias,
    u16* __restrict__ Cb, float* __restrict__ Cf,
    const float* __restrict__ xres)
{
    __shared__ __align__(16) u16 Bt[64 * 256];
    int tid = threadIdx.x;
    int lane = tid & 63, wave = tid >> 6;
    int m0 = blockIdx.y * 64 + wave * 16;
    int n0 = blockIdx.x * 64;

    #pragma unroll
    for (int i = 0; i < 8; i++) {
        int G = i * 256 + tid;
        int row = G >> 5, g = G & 31;
        const u16* src = Bm + (size_t)(n0 + row) * 256 + ((g ^ (row & 7)) << 3);
        gld_lds16(src, Bt + (size_t)(i * 256 + wave * 64) * 8);
    }

    int lr = lane & 15, hk = lane >> 4, lk = hk * 8;
    int ksw = lr & 7;
    const u16* Ap = A + (size_t)(m0 + lr) * 256 + lk;
    bf16x8 af[8];
    #pragma unroll
    for (int kk = 0; kk < 8; kk++) af[kk] = ldb8(Ap + kk * 32);

    __syncthreads();

    f32x4 acc[4] = {};
    #pragma unroll
    for (int kk = 0; kk < 8; kk++) {
        #pragma unroll
        for (int nt = 0; nt < 4; nt++) {
            int row = nt * 16 + lr;
            int g = (kk * 4 + hk) ^ ksw;
            bf16x8 bf = ldb8(Bt + (size_t)(row * 32 + g) * 8);
            acc[nt] = __builtin_amdgcn_mfma_f32_16x16x32_bf16(af[kk], bf, acc[nt], 0, 0, 0);
        }
    }
    int rbase = m0 + (hk << 2);
    #pragma unroll
    for (int nt = 0; nt < 4; nt++) {
        int col = n0 + nt * 16 + lr;
        #pragma unroll
        for (int j = 0; j < 4; j++) {
            int row = rbase + j;
            float v = acc[nt][j];
            if (MODE == 0) {
                v += bias[col];
                Cb[(size_t)row * 256 + col] = f2bf(v);
            } else {
                int b = col >> 10, p = col & 1023;
                size_t off = (size_t)b * (CH * HWPX) + (size_t)row * 1024 + p;
                v += bias[row];
                if (MODE == 1) Cb[off] = f2bf(v);
                else           Cf[off] = v + xres[off];
            }
        }
    }
}

// ---------------- K3: flash attention, KV-split + shuffle-free defer-max ----------------
template <int NH>
__global__ __launch_bounds__(256) void attn(
    const u16* __restrict__ Qt, const u16* __restrict__ Kt,
    const u16* __restrict__ Vc, u16* __restrict__ O0,
    u16* __restrict__ O1, float* __restrict__ ML)
{
    __shared__ __align__(16) u16 Kbuf[2][32 * 256];   // 32 KB
    __shared__ __align__(16) u16 Vbuf[256 * 32];      // 16 KB
    __shared__ __align__(16) u16 Pbuf[4][16 * 32];    // 4 KB  -> total 52 KB exact

    int tid = threadIdx.x;
    int lane = tid & 63, wave = tid >> 6;
    int bid = blockIdx.x;
    int b, qb, h;
    if (NH == 2) {
        // XCD-gathered: XCD x hosts batches {x, x+8, x+16, x+24}; halves adjacent
        int x = bid & 7, L = bid >> 3;       // L in 0..127
        b  = x + 8 * (L >> 5);
        qb = (L & 31) >> 1;
        h  = L & 1;
    } else {
        b = (bid & 7) + ((bid >> 7) << 3);
        qb = (bid >> 3) & 15;
        h = 0;
    }
    const int NSTEP = (1024 / NH) / 32;

    const u16* Qb = Qt + (size_t)b * (HWPX * CH);
    const u16* Kb = Kt + (size_t)b * (HWPX * CH) + (size_t)h * 512 * 256;
    const u16* Vb = Vc + (size_t)b * (CH * HWPX) + (size_t)h * 512;
    int q0 = qb * 64 + wave * 16;
    int lr = lane & 15, hk = lane >> 4, lk = hk * 8;
    int ksw = lr & 7;

    int koff[4], voff[4];
    #pragma unroll
    for (int i = 0; i < 4; i++) {
        int G = i * 256 + tid;
        int kr = G >> 5, kg = G & 31;
        koff[i] = kr * 256 + ((kg ^ (kr & 7)) << 3);
        int vr = G >> 2, vg = G & 3;
        voff[i] = vr * 1024 + ((vg ^ ((vr >> 1) & 3)) << 3);
    }

    bf16x8 qf[8];
    #pragma unroll
    for (int kk = 0; kk < 8; kk++)
        qf[kk] = ldb8(Qb + (size_t)(q0 + lr) * 256 + kk * 32 + lk);

    f32x4 oa[16] = {};
    float m_run[4] = {-1e30f, -1e30f, -1e30f, -1e30f};
    float l_run[4] = {0.f, 0.f, 0.f, 0.f};   // lane-partial (cols lr, lr+16)
    u16* Pw = Pbuf[wave];

    #pragma unroll
    for (int i = 0; i < 4; i++)
        gld_lds16(Kb + koff[i], Kbuf[0] + (size_t)(i * 256 + wave * 64) * 8);

    for (int t = 0; t < NSTEP; ++t) {
        int kcur = t & 1;
        __syncthreads();   // B1: K(t) staged; Vbuf/P of t-1 consumed

        if (t < NSTEP - 1) {
            u16* kd = Kbuf[0] + (size_t)(kcur ^ 1) * (32 * 256);
            const u16* ks = Kb + (t + 1) * (32 * 256);
            #pragma unroll
            for (int i = 0; i < 4; i++)
                gld_lds16(ks + koff[i], kd + (size_t)(i * 256 + wave * 64) * 8);
        }
        {
            const u16* vs = Vb + t * 32;
            #pragma unroll
            for (int i = 0; i < 4; i++)
                gld_lds16(vs + voff[i], Vbuf + (size_t)(i * 256 + wave * 64) * 8);
        }

        // ---- QK^T (log2 domain; Q pre-scaled by log2e/16) ----
        const u16* krd = Kbuf[0] + (size_t)kcur * (32 * 256);
        f32x4 sacc[2] = {};
        #pragma unroll
        for (int kk = 0; kk < 8; kk++) {
            #pragma unroll
            for (int nt = 0; nt < 2; nt++) {
                int row = nt * 16 + lr;
                int g = (kk * 4 + hk) ^ ksw;
                bf16x8 kf = ldb8(krd + (size_t)(row * 32 + g) * 8);
                sacc[nt] = __builtin_amdgcn_mfma_f32_16x16x32_bf16(qf[kk], kf, sacc[nt], 0, 0, 0);
            }
        }

        // ---- shuffle-free defer-max online softmax ----
        float mloc[4];
        bool st = true;
        #pragma unroll
        for (int j = 0; j < 4; j++) {
            mloc[j] = fmaxf(sacc[0][j], sacc[1][j]);
            st = st && (mloc[j] - m_run[j] <= 4.f);
        }
        if (!__all(st)) {                       // rare: t==0 or max jumped > 4
            float sc[4];
            #pragma unroll
            for (int j = 0; j < 4; j++) {
                float mx = mloc[j];
                #pragma unroll
                for (int d2 = 1; d2 < 16; d2 <<= 1) mx = fmaxf(mx, __shfl_xor(mx, d2));
                float mn = fmaxf(m_run[j], mx);
                sc[j] = exp2f(m_run[j] - mn);
                m_run[j] = mn;
                l_run[j] *= sc[j];
            }
            #pragma unroll
            for (int ct = 0; ct < 16; ct++) {
                f32x4 tacc = oa[ct];
                tacc[0] *= sc[0]; tacc[1] *= sc[1]; tacc[2] *= sc[2]; tacc[3] *= sc[3];
                oa[ct] = tacc;
            }
        }
        #pragma unroll
        for (int j = 0; j < 4; j++) {
            float p0 = exp2f(sacc[0][j] - m_run[j]);   // bounded by 2^4
            float p1 = exp2f(sacc[1][j] - m_run[j]);
            l_run[j] += p0 + p1;                        // lane-partial sum
            Pw[(hk * 4 + j) * 32 + lr]      = f2bf(p0);
            Pw[(hk * 4 + j) * 32 + 16 + lr] = f2bf(p1);
        }

        __syncthreads();   // B2: V(t)+K(t+1) staged; P visible

        // ---- PV ----
        bf16x8 pf = ldb8(Pw + lr * 32 + lk);
        int vsw = (lr >> 1) & 3;
        #pragma unroll
        for (int ct = 0; ct < 16; ct++) {
            int row = ct * 16 + lr;
            int vg = hk ^ vsw;
            bf16x8 vf = ldb8(Vbuf + (size_t)(row * 4 + vg) * 8);
            oa[ct] = __builtin_amdgcn_mfma_f32_16x16x32_bf16(pf, vf, oa[ct], 0, 0, 0);
        }
    }

    // final l reduction (deferred from the loop)
    #pragma unroll
    for (int j = 0; j < 4; j++) {
        float l = l_run[j];
        #pragma unroll
        for (int d2 = 1; d2 < 16; d2 <<= 1) l += __shfl_xor(l, d2);
        l_run[j] = l;
    }
    float rinv[4];
    #pragma unroll
    for (int j = 0; j < 4; j++) rinv[j] = 1.f / l_run[j];
    u16* Ob = ((NH == 2 && h == 1) ? O1 : O0) + (size_t)b * (HWPX * CH);
    #pragma unroll
    for (int ct = 0; ct < 16; ct++) {
        #pragma unroll
        for (int j = 0; j < 4; j++) {
            Ob[(size_t)(q0 + hk * 4 + j) * 256 + ct * 16 + lr] = f2bf(oa[ct][j] * rinv[j]);
        }
    }
    if (NH == 2 && lr == 0) {
        #pragma unroll
        for (int j = 0; j < 4; j++) {
            int qrow = q0 + hk * 4 + j;
            size_t idx = ((size_t)h * 32768 + (size_t)b * 1024 + qrow) * 2;
            ML[idx] = m_run[j];
            ML[idx + 1] = l_run[j];
        }
    }
}

// ---------------- K3b: merge the two KV-halves (in place into O0) ----------------
__global__ __launch_bounds__(256) void merge_halves(
    u16* __restrict__ O0, const u16* __restrict__ O1, const float* __restrict__ ML)
{
    int gid = blockIdx.x * 256 + threadIdx.x;   // 32 threads per row
    int row = gid >> 5;
    int c8  = (gid & 31) << 3;
    float m0 = ML[row * 2], l0 = ML[row * 2 + 1];
    float m1 = ML[(32768 + row) * 2], l1 = ML[(32768 + row) * 2 + 1];
    float m  = fmaxf(m0, m1);
    float w0 = l0 * exp2f(m0 - m), w1 = l1 * exp2f(m1 - m);
    float inv = 1.f / (w0 + w1);
    w0 *= inv; w1 *= inv;
    u16* p0 = O0 + (size_t)row * 256 + c8;
    const u16* p1 = O1 + (size_t)row * 256 + c8;
    u16x8 a = *(const u16x8*)p0;
    u16x8 c = *(const u16x8*)p1;
    u16x8 r;
    #pragma unroll
    for (int i = 0; i < 8; i++) r[i] = f2bf(w0 * bf2f(a[i]) + w1 * bf2f(c[i]));
    *(u16x8*)p0 = r;
}

// ---------------- host launch ----------------
extern "C" void kernel_launch(void* const* d_in, const int* in_sizes, int n_in,
                              void* d_out, int out_size, void* d_ws, size_t ws_size,
                              hipStream_t stream)
{
    const float* x   = (const float*)d_in[0];
    const float* Wq  = (const float*)d_in[1];
    const float* bq  = (const float*)d_in[2];
    const float* Wk  = (const float*)d_in[3];
    const float* bk  = (const float*)d_in[4];
    const float* Wv  = (const float*)d_in[5];
    const float* bv  = (const float*)d_in[6];
    const float* Wo  = (const float*)d_in[7];
    const float* bo  = (const float*)d_in[8];
    const float* gqs = (const float*)d_in[9];
    const float* gqb = (const float*)d_in[10];
    const float* gks = (const float*)d_in[11];
    const float* gkb = (const float*)d_in[12];
    const float* gvs = (const float*)d_in[13];
    const float* gvb = (const float*)d_in[14];

    const size_t BIGB = (size_t)NB * HWPX * CH * 2;          // 16 MB per bf16 buffer
    const size_t WTB  = 4 * 65536 * 2;                       // 512 KB
    const size_t BIASB = 4 * 256 * 4;                        // 4 KB
    const size_t MLB  = 2 * 32768 * 2 * 4;                   // 512 KB
    size_t need_base  = 4 * BIGB + WTB + BIASB;
    size_t need_split = need_base + BIGB + MLB;
    if (ws_size < need_base) return;

    char* w = (char*)d_ws;
    u16*  Xh   = (u16*)(w);                    // [B][p][c]; O-half0 after V proj
    u16*  Qt   = (u16*)(w + BIGB);
    u16*  Kt   = (u16*)(w + 2 * BIGB);
    u16*  Vc   = (u16*)(w + 3 * BIGB);
    u16*  Wt   = (u16*)(w + 4 * BIGB);
    float* bias = (float*)(w + 4 * BIGB + WTB);
    u16*  O1   = (u16*)(w + 4 * BIGB + WTB + BIASB);
    float* ML  = (float*)(w + 4 * BIGB + WTB + BIASB + BIGB);

    wprep<<<dim3(1024), dim3(256), 0, stream>>>(Wq, bq, gqs, gqb, Wk, bk, gks, gkb,
                                                Wv, bv, gvs, gvb, Wo, bo, Wt, bias);
    gn_kernel<<<dim3(1024), dim3(256), 0, stream>>>(x, Xh);

    gemm_nt<0><<<dim3(4, 512), dim3(256), 0, stream>>>(Xh, Wt,           bias,       Qt, nullptr, nullptr);
    gemm_nt<0><<<dim3(4, 512), dim3(256), 0, stream>>>(Xh, Wt + 65536,   bias + 256, Kt, nullptr, nullptr);
    gemm_nt<1><<<dim3(512, 4), dim3(256), 0, stream>>>(Wt + 131072, Xh,  bias + 512, Vc, nullptr, nullptr);

    if (ws_size >= need_split) {
        attn<2><<<dim3(1024), dim3(256), 0, stream>>>(Qt, Kt, Vc, Xh, O1, ML);
        merge_halves<<<dim3(4096), dim3(256), 0, stream>>>(Xh, O1, ML);
    } else {
        attn<1><<<dim3(512), dim3(256), 0, stream>>>(Qt, Kt, Vc, Xh, nullptr, nullptr);
    }

    gemm_nt<2><<<dim3(512, 4), dim3(256), 0, stream>>>(Wt + 196608, Xh,  bias + 768, nullptr, (float*)d_out, x);
}

// Round 5
// 200.601 us; speedup vs baseline: 1.1946x; 1.0962x over previous
//
#include <hip/hip_runtime.h>
#include <stdint.h>

// B=32, C=256, H=W=32 (HW=1024), GROUPS=32, EPS=1e-5.
// K0 wprep : Wt[d][c] = gs[c]*W[c][d]*scale (bf16); bias[d]=(b[d]+sum_c gb[c]W[c][d])*scale
//            q-scale = log2(e)/16  (folds softmax 1/sqrt(C) AND exp->exp2 domain)
// K1 gn    : Xh[b][p][c] = (x-mu)*rsqrt(var+eps) (bf16)
// K2 gemmNT: shared B-tile staged via global_load_lds, XOR-swizzled
// K3 attn  : flash attn, ONE barrier per 32-wide KV step:
//            K dbuf via global_load_lds (XOR-swizzled src), V dbuf via reg-staging
//            into padded [256][40] LDS (conflict-free), P per-wave private (pad 40),
//            shuffle-free defer-max softmax. Prefetch distance = full step.
// K4 gemmNT: out = x + Wo^T O + bo (fp32)

#define NB 32
#define CH 256
#define HWPX 1024

typedef __bf16 bf16x8 __attribute__((ext_vector_type(8)));
typedef float f32x4 __attribute__((ext_vector_type(4)));
typedef unsigned short u16;
typedef u16 u16x8 __attribute__((ext_vector_type(8)));

__device__ __forceinline__ u16 f2bf(float f) {
    __bf16 h = (__bf16)f;
    return __builtin_bit_cast(u16, h);
}
__device__ __forceinline__ bf16x8 ldb8(const u16* p) {
    return __builtin_bit_cast(bf16x8, *(const u16x8*)p);
}
__device__ __forceinline__ void gld_lds16(const u16* g, u16* l) {
    __builtin_amdgcn_global_load_lds(
        (const __attribute__((address_space(1))) void*)g,
        (__attribute__((address_space(3))) void*)l, 16, 0, 0);
}

// ---------------- K0: weight prep ----------------
__global__ __launch_bounds__(256) void wprep(
    const float* __restrict__ Wq, const float* __restrict__ bq,
    const float* __restrict__ gqs, const float* __restrict__ gqb,
    const float* __restrict__ Wk, const float* __restrict__ bk,
    const float* __restrict__ gks, const float* __restrict__ gkb,
    const float* __restrict__ Wv, const float* __restrict__ bv,
    const float* __restrict__ gvs, const float* __restrict__ gvb,
    const float* __restrict__ Wo, const float* __restrict__ bo,
    u16* __restrict__ Wt, float* __restrict__ bias)
{
    int m = blockIdx.x >> 8;
    int d = blockIdx.x & 255;
    int c = threadIdx.x;
    const float *W, *bb, *gs, *gb; float scale;
    const float QSC = 0.09016844005556021f;   // log2(e)/16
    if (m == 0)      { W = Wq; bb = bq; gs = gqs; gb = gqb; scale = QSC; }
    else if (m == 1) { W = Wk; bb = bk; gs = gks; gb = gkb; scale = 1.f; }
    else if (m == 2) { W = Wv; bb = bv; gs = gvs; gb = gvb; scale = 1.f; }
    else             { W = Wo; bb = bo; gs = nullptr; gb = nullptr; scale = 1.f; }
    float w   = W[c * 256 + d];
    float gsc = gs ? gs[c] : 1.f;
    float gbc = gb ? gb[c] : 0.f;
    Wt[((size_t)m << 16) + d * 256 + c] = f2bf(w * gsc * scale);
    __shared__ float red[256];
    red[c] = gbc * w;
    __syncthreads();
    for (int s = 128; s > 0; s >>= 1) { if (c < s) red[c] += red[c + s]; __syncthreads(); }
    if (c == 0) bias[m * 256 + d] = (bb[d] + red[0]) * scale;
}

// ---------------- K1: groupnorm ----------------
__global__ __launch_bounds__(256) void gn_kernel(const float* __restrict__ x,
                                                 u16* __restrict__ Xh)
{
    int blk = blockIdx.x;
    int b = blk >> 5, g = blk & 31;
    const float* base = x + (size_t)(b * 256 + g * 8) * 1024;
    int t = threadIdx.x;
    float s = 0.f, s2 = 0.f;
    for (int i = 0; i < 32; i++) { float v = base[t + i * 256]; s += v; s2 += v * v; }
    __shared__ float rs[256], rq[256];
    rs[t] = s; rq[t] = s2;
    __syncthreads();
    for (int k = 128; k > 0; k >>= 1) {
        if (t < k) { rs[t] += rs[t + k]; rq[t] += rq[t + k]; }
        __syncthreads();
    }
    float mu  = rs[0] * (1.f / 8192.f);
    float var = rq[0] * (1.f / 8192.f) - mu * mu;
    float rv  = rsqrtf(var + 1e-5f);
    u16* outp = Xh + (size_t)b * (HWPX * CH) + g * 8;
    for (int it = 0; it < 4; it++) {
        int p = t + it * 256;
        u16x8 tv;
        #pragma unroll
        for (int c2 = 0; c2 < 8; c2++) tv[c2] = f2bf((base[c2 * 1024 + p] - mu) * rv);
        *(u16x8*)(outp + (size_t)p * 256) = tv;
    }
}

// ---------------- K2/K4: NT GEMM, shared B-tile in LDS ----------------
template <int MODE>
__global__ __launch_bounds__(256) void gemm_nt(
    const u16* __restrict__ A, const u16* __restrict__ Bm,
    const float* __restrict__ bias,
    u16* __restrict__ Cb, float* __restrict__ Cf,
    const float* __restrict__ xres)
{
    __shared__ __align__(16) u16 Bt[64 * 256];
    int tid = threadIdx.x;
    int lane = tid & 63, wave = tid >> 6;
    int m0 = blockIdx.y * 64 + wave * 16;
    int n0 = blockIdx.x * 64;

    #pragma unroll
    for (int i = 0; i < 8; i++) {
        int G = i * 256 + tid;
        int row = G >> 5, g = G & 31;
        const u16* src = Bm + (size_t)(n0 + row) * 256 + ((g ^ (row & 7)) << 3);
        gld_lds16(src, Bt + (size_t)(i * 256 + wave * 64) * 8);
    }

    int lr = lane & 15, hk = lane >> 4, lk = hk * 8;
    int ksw = lr & 7;
    const u16* Ap = A + (size_t)(m0 + lr) * 256 + lk;
    bf16x8 af[8];
    #pragma unroll
    for (int kk = 0; kk < 8; kk++) af[kk] = ldb8(Ap + kk * 32);

    __syncthreads();

    f32x4 acc[4] = {};
    #pragma unroll
    for (int kk = 0; kk < 8; kk++) {
        #pragma unroll
        for (int nt = 0; nt < 4; nt++) {
            int row = nt * 16 + lr;
            int g = (kk * 4 + hk) ^ ksw;
            bf16x8 bf = ldb8(Bt + (size_t)(row * 32 + g) * 8);
            acc[nt] = __builtin_amdgcn_mfma_f32_16x16x32_bf16(af[kk], bf, acc[nt], 0, 0, 0);
        }
    }
    int rbase = m0 + (hk << 2);
    #pragma unroll
    for (int nt = 0; nt < 4; nt++) {
        int col = n0 + nt * 16 + lr;
        #pragma unroll
        for (int j = 0; j < 4; j++) {
            int row = rbase + j;
            float v = acc[nt][j];
            if (MODE == 0) {
                v += bias[col];
                Cb[(size_t)row * 256 + col] = f2bf(v);
            } else {
                int b = col >> 10, p = col & 1023;
                size_t off = (size_t)b * (CH * HWPX) + (size_t)row * 1024 + p;
                v += bias[row];
                if (MODE == 1) Cb[off] = f2bf(v);
                else           Cf[off] = v + xres[off];
            }
        }
    }
}

// ---------------- K3: flash attention, single barrier per step ----------------
// grid 512, 4 waves x 16 q-rows, KV step 32, 32 steps.
#define VPAD 40
__global__ __launch_bounds__(256) void attn(
    const u16* __restrict__ Qt, const u16* __restrict__ Kt,
    const u16* __restrict__ Vc, u16* __restrict__ O)
{
    __shared__ __align__(16) u16 Kbuf[2][32 * 256];     // 32 KB, XOR-swizzled granules
    __shared__ __align__(16) u16 Vbuf[2][256 * VPAD];   // 40 KB, padded rows (80 B)
    __shared__ __align__(16) u16 Pbuf[4][16 * VPAD];    // 5 KB

    int tid = threadIdx.x;
    int lane = tid & 63, wave = tid >> 6;
    int bid = blockIdx.x;
    int b  = (bid & 7) + ((bid >> 7) << 3);
    int qb = (bid >> 3) & 15;

    const u16* Qb = Qt + (size_t)b * (HWPX * CH);
    const u16* Kb = Kt + (size_t)b * (HWPX * CH);
    const u16* Vb = Vc + (size_t)b * (CH * HWPX);
    int q0 = qb * 64 + wave * 16;
    int lr = lane & 15, hk = lane >> 4, lk = hk * 8;
    int ksw = lr & 7;

    // K staging: src XOR-pre-swizzled, LDS dest linear (1 KB/wave-inst)
    int koff[4];
    // V staging: linear global load -> reg -> padded LDS write
    int vrow[4], vgr[4];
    #pragma unroll
    for (int i = 0; i < 4; i++) {
        int G = i * 256 + tid;
        int kr = G >> 5, kg = G & 31;
        koff[i] = kr * 256 + ((kg ^ (kr & 7)) << 3);
        vrow[i] = G >> 2; vgr[i] = G & 3;
    }

    bf16x8 qf[8];
    #pragma unroll
    for (int kk = 0; kk < 8; kk++)
        qf[kk] = ldb8(Qb + (size_t)(q0 + lr) * 256 + kk * 32 + lk);

    f32x4 oa[16] = {};
    float m_run[4] = {-1e30f, -1e30f, -1e30f, -1e30f};
    float l_run[4] = {0.f, 0.f, 0.f, 0.f};   // lane-partial
    u16* Pw = Pbuf[wave];

    // prologue: stage K(0), V(0)
    u16x8 vreg[4];
    #pragma unroll
    for (int i = 0; i < 4; i++)
        vreg[i] = *(const u16x8*)(Vb + (size_t)vrow[i] * 1024 + vgr[i] * 8);
    #pragma unroll
    for (int i = 0; i < 4; i++)
        gld_lds16(Kb + koff[i], Kbuf[0] + (size_t)(i * 256 + wave * 64) * 8);
    #pragma unroll
    for (int i = 0; i < 4; i++)
        *(u16x8*)(&Vbuf[0][vrow[i] * VPAD + vgr[i] * 8]) = vreg[i];
    __syncthreads();

    for (int t = 0; t < 32; ++t) {
        int cur = t & 1;
        // ---- prefetch t+1 (drained at the barrier ending this step) ----
        if (t < 31) {
            const u16* vs = Vb + (t + 1) * 32;
            #pragma unroll
            for (int i = 0; i < 4; i++)
                vreg[i] = *(const u16x8*)(vs + (size_t)vrow[i] * 1024 + vgr[i] * 8);
            u16* kd = Kbuf[cur ^ 1];
            const u16* ks = Kb + (t + 1) * (32 * 256);
            #pragma unroll
            for (int i = 0; i < 4; i++)
                gld_lds16(ks + koff[i], kd + (size_t)(i * 256 + wave * 64) * 8);
        }

        // ---- QK^T (log2 domain; Q pre-scaled by log2e/16) ----
        const u16* krd = Kbuf[cur];
        f32x4 sacc[2] = {};
        #pragma unroll
        for (int kk = 0; kk < 8; kk++) {
            #pragma unroll
            for (int nt = 0; nt < 2; nt++) {
                int row = nt * 16 + lr;
                int g = (kk * 4 + hk) ^ ksw;
                bf16x8 kf = ldb8(krd + (size_t)(row * 32 + g) * 8);
                sacc[nt] = __builtin_amdgcn_mfma_f32_16x16x32_bf16(qf[kk], kf, sacc[nt], 0, 0, 0);
            }
        }

        // ---- shuffle-free defer-max online softmax ----
        float mloc[4];
        bool st = true;
        #pragma unroll
        for (int j = 0; j < 4; j++) {
            mloc[j] = fmaxf(sacc[0][j], sacc[1][j]);
            st = st && (mloc[j] - m_run[j] <= 4.f);
        }
        if (!__all(st)) {                       // rare: t==0 or max jumped > 4
            float sc[4];
            #pragma unroll
            for (int j = 0; j < 4; j++) {
                float mx = mloc[j];
                #pragma unroll
                for (int d2 = 1; d2 < 16; d2 <<= 1) mx = fmaxf(mx, __shfl_xor(mx, d2));
                float mn = fmaxf(m_run[j], mx);
                sc[j] = exp2f(m_run[j] - mn);
                m_run[j] = mn;
                l_run[j] *= sc[j];
            }
            #pragma unroll
            for (int ct = 0; ct < 16; ct++) {
                f32x4 tacc = oa[ct];
                tacc[0] *= sc[0]; tacc[1] *= sc[1]; tacc[2] *= sc[2]; tacc[3] *= sc[3];
                oa[ct] = tacc;
            }
        }
        #pragma unroll
        for (int j = 0; j < 4; j++) {
            float p0 = exp2f(sacc[0][j] - m_run[j]);   // bounded by 2^4
            float p1 = exp2f(sacc[1][j] - m_run[j]);
            l_run[j] += p0 + p1;
            Pw[(hk * 4 + j) * VPAD + lr]      = f2bf(p0);
            Pw[(hk * 4 + j) * VPAD + 16 + lr] = f2bf(p1);
        }

        // ---- PV (P is per-wave private: lgkmcnt ordering only, no barrier) ----
        bf16x8 pf = ldb8(Pw + lr * VPAD + lk);
        const u16* vrd = Vbuf[cur];
        #pragma unroll
        for (int ct = 0; ct < 16; ct++) {
            int row = ct * 16 + lr;
            bf16x8 vf = ldb8(vrd + (size_t)row * VPAD + lk);
            oa[ct] = __builtin_amdgcn_mfma_f32_16x16x32_bf16(pf, vf, oa[ct], 0, 0, 0);
        }

        // ---- write V(t+1) regs -> LDS (loads had the whole step to land) ----
        if (t < 31) {
            #pragma unroll
            for (int i = 0; i < 4; i++)
                *(u16x8*)(&Vbuf[cur ^ 1][vrow[i] * VPAD + vgr[i] * 8]) = vreg[i];
        }
        __syncthreads();   // ONE barrier/step: K(t+1)+V(t+1) ready, all reads of t done
    }

    // final l reduction (deferred from the loop)
    #pragma unroll
    for (int j = 0; j < 4; j++) {
        float l = l_run[j];
        #pragma unroll
        for (int d2 = 1; d2 < 16; d2 <<= 1) l += __shfl_xor(l, d2);
        l_run[j] = l;
    }
    float rinv[4];
    #pragma unroll
    for (int j = 0; j < 4; j++) rinv[j] = 1.f / l_run[j];
    u16* Ob = O + (size_t)b * (HWPX * CH);
    #pragma unroll
    for (int ct = 0; ct < 16; ct++) {
        #pragma unroll
        for (int j = 0; j < 4; j++) {
            Ob[(size_t)(q0 + hk * 4 + j) * 256 + ct * 16 + lr] = f2bf(oa[ct][j] * rinv[j]);
        }
    }
}

// ---------------- host launch ----------------
extern "C" void kernel_launch(void* const* d_in, const int* in_sizes, int n_in,
                              void* d_out, int out_size, void* d_ws, size_t ws_size,
                              hipStream_t stream)
{
    const float* x   = (const float*)d_in[0];
    const float* Wq  = (const float*)d_in[1];
    const float* bq  = (const float*)d_in[2];
    const float* Wk  = (const float*)d_in[3];
    const float* bk  = (const float*)d_in[4];
    const float* Wv  = (const float*)d_in[5];
    const float* bv  = (const float*)d_in[6];
    const float* Wo  = (const float*)d_in[7];
    const float* bo  = (const float*)d_in[8];
    const float* gqs = (const float*)d_in[9];
    const float* gqb = (const float*)d_in[10];
    const float* gks = (const float*)d_in[11];
    const float* gkb = (const float*)d_in[12];
    const float* gvs = (const float*)d_in[13];
    const float* gvb = (const float*)d_in[14];

    const size_t BIGB = (size_t)NB * HWPX * CH * 2;          // 16 MB per bf16 buffer
    const size_t WTB  = 4 * 65536 * 2;                       // 512 KB
    const size_t BIASB = 4 * 256 * 4;                        // 4 KB
    size_t need = 4 * BIGB + WTB + BIASB;
    if (ws_size < need) return;

    char* w = (char*)d_ws;
    u16*  Xh   = (u16*)(w);                    // [B][p][c]; reused as O after V proj
    u16*  Qt   = (u16*)(w + BIGB);
    u16*  Kt   = (u16*)(w + 2 * BIGB);
    u16*  Vc   = (u16*)(w + 3 * BIGB);
    u16*  Wt   = (u16*)(w + 4 * BIGB);
    float* bias = (float*)(w + 4 * BIGB + WTB);

    wprep<<<dim3(1024), dim3(256), 0, stream>>>(Wq, bq, gqs, gqb, Wk, bk, gks, gkb,
                                                Wv, bv, gvs, gvb, Wo, bo, Wt, bias);
    gn_kernel<<<dim3(1024), dim3(256), 0, stream>>>(x, Xh);

    gemm_nt<0><<<dim3(4, 512), dim3(256), 0, stream>>>(Xh, Wt,           bias,       Qt, nullptr, nullptr);
    gemm_nt<0><<<dim3(4, 512), dim3(256), 0, stream>>>(Xh, Wt + 65536,   bias + 256, Kt, nullptr, nullptr);
    gemm_nt<1><<<dim3(512, 4), dim3(256), 0, stream>>>(Wt + 131072, Xh,  bias + 512, Vc, nullptr, nullptr);
    attn<<<dim3(512), dim3(256), 0, stream>>>(Qt, Kt, Vc, Xh);
    gemm_nt<2><<<dim3(512, 4), dim3(256), 0, stream>>>(Wt + 196608, Xh,  bias + 768, nullptr, (float*)d_out, x);
}

// Round 6
// 159.600 us; speedup vs baseline: 1.5014x; 1.2569x over previous
//
#include <hip/hip_runtime.h>
#include <stdint.h>

// B=32, C=256, H=W=32 (HW=1024), GROUPS=32, EPS=1e-5.
// K0 wprep : Wt[d][c] = gs[c]*W[c][d]*scale (bf16); bias[d]=(b[d]+sum_c gb[c]W[c][d])*scale
//            q-scale = log2(e)/16  (folds softmax 1/sqrt(C) AND exp->exp2 domain)
// K1 gn    : Xh[b][p][c] = (x-mu)*rsqrt(var+eps) (bf16)
// K2 gemmNT: shared B-tile staged via global_load_lds, XOR-swizzled
// K3 attn  : 32x32x16 MFMA, swapped QK (S^T), lane-local softmax, P in regs,
//            K/V dbuf LDS (64KB), 1 barrier/step, grid 256 (1 block/CU).
// K4 gemmNT: out = x + Wo^T O + bo (fp32)

#define NB 32
#define CH 256
#define HWPX 1024

typedef __bf16 bf16x8 __attribute__((ext_vector_type(8)));
typedef float f32x4 __attribute__((ext_vector_type(4)));
typedef float f32x16 __attribute__((ext_vector_type(16)));
typedef unsigned short u16;
typedef unsigned int u32;
typedef u16 u16x4 __attribute__((ext_vector_type(4)));
typedef u16 u16x8 __attribute__((ext_vector_type(8)));
typedef u32 u32x4 __attribute__((ext_vector_type(4)));

__device__ __forceinline__ u16 f2bf(float f) {
    __bf16 h = (__bf16)f;
    return __builtin_bit_cast(u16, h);
}
__device__ __forceinline__ u32 pk2(float a, float b) {
    return ((u32)f2bf(b) << 16) | (u32)f2bf(a);
}
__device__ __forceinline__ bf16x8 ldb8(const u16* p) {
    return __builtin_bit_cast(bf16x8, *(const u16x8*)p);
}
__device__ __forceinline__ void gld_lds16(const u16* g, u16* l) {
    __builtin_amdgcn_global_load_lds(
        (const __attribute__((address_space(1))) void*)g,
        (__attribute__((address_space(3))) void*)l, 16, 0, 0);
}

// ---------------- K0: weight prep ----------------
__global__ __launch_bounds__(256) void wprep(
    const float* __restrict__ Wq, const float* __restrict__ bq,
    const float* __restrict__ gqs, const float* __restrict__ gqb,
    const float* __restrict__ Wk, const float* __restrict__ bk,
    const float* __restrict__ gks, const float* __restrict__ gkb,
    const float* __restrict__ Wv, const float* __restrict__ bv,
    const float* __restrict__ gvs, const float* __restrict__ gvb,
    const float* __restrict__ Wo, const float* __restrict__ bo,
    u16* __restrict__ Wt, float* __restrict__ bias)
{
    int m = blockIdx.x >> 8;
    int d = blockIdx.x & 255;
    int c = threadIdx.x;
    const float *W, *bb, *gs, *gb; float scale;
    const float QSC = 0.09016844005556021f;   // log2(e)/16
    if (m == 0)      { W = Wq; bb = bq; gs = gqs; gb = gqb; scale = QSC; }
    else if (m == 1) { W = Wk; bb = bk; gs = gks; gb = gkb; scale = 1.f; }
    else if (m == 2) { W = Wv; bb = bv; gs = gvs; gb = gvb; scale = 1.f; }
    else             { W = Wo; bb = bo; gs = nullptr; gb = nullptr; scale = 1.f; }
    float w   = W[c * 256 + d];
    float gsc = gs ? gs[c] : 1.f;
    float gbc = gb ? gb[c] : 0.f;
    Wt[((size_t)m << 16) + d * 256 + c] = f2bf(w * gsc * scale);
    __shared__ float red[256];
    red[c] = gbc * w;
    __syncthreads();
    for (int s = 128; s > 0; s >>= 1) { if (c < s) red[c] += red[c + s]; __syncthreads(); }
    if (c == 0) bias[m * 256 + d] = (bb[d] + red[0]) * scale;
}

// ---------------- K1: groupnorm ----------------
__global__ __launch_bounds__(256) void gn_kernel(const float* __restrict__ x,
                                                 u16* __restrict__ Xh)
{
    int blk = blockIdx.x;
    int b = blk >> 5, g = blk & 31;
    const float* base = x + (size_t)(b * 256 + g * 8) * 1024;
    int t = threadIdx.x;
    float s = 0.f, s2 = 0.f;
    for (int i = 0; i < 32; i++) { float v = base[t + i * 256]; s += v; s2 += v * v; }
    __shared__ float rs[256], rq[256];
    rs[t] = s; rq[t] = s2;
    __syncthreads();
    for (int k = 128; k > 0; k >>= 1) {
        if (t < k) { rs[t] += rs[t + k]; rq[t] += rq[t + k]; }
        __syncthreads();
    }
    float mu  = rs[0] * (1.f / 8192.f);
    float var = rq[0] * (1.f / 8192.f) - mu * mu;
    float rv  = rsqrtf(var + 1e-5f);
    u16* outp = Xh + (size_t)b * (HWPX * CH) + g * 8;
    for (int it = 0; it < 4; it++) {
        int p = t + it * 256;
        u16x8 tv;
        #pragma unroll
        for (int c2 = 0; c2 < 8; c2++) tv[c2] = f2bf((base[c2 * 1024 + p] - mu) * rv);
        *(u16x8*)(outp + (size_t)p * 256) = tv;
    }
}

// ---------------- K2/K4: NT GEMM, shared B-tile in LDS ----------------
template <int MODE>
__global__ __launch_bounds__(256) void gemm_nt(
    const u16* __restrict__ A, const u16* __restrict__ Bm,
    const float* __restrict__ bias,
    u16* __restrict__ Cb, float* __restrict__ Cf,
    const float* __restrict__ xres)
{
    __shared__ __align__(16) u16 Bt[64 * 256];
    int tid = threadIdx.x;
    int lane = tid & 63, wave = tid >> 6;
    int m0 = blockIdx.y * 64 + wave * 16;
    int n0 = blockIdx.x * 64;

    #pragma unroll
    for (int i = 0; i < 8; i++) {
        int G = i * 256 + tid;
        int row = G >> 5, g = G & 31;
        const u16* src = Bm + (size_t)(n0 + row) * 256 + ((g ^ (row & 7)) << 3);
        gld_lds16(src, Bt + (size_t)(i * 256 + wave * 64) * 8);
    }

    int lr = lane & 15, hk = lane >> 4, lk = hk * 8;
    int ksw = lr & 7;
    const u16* Ap = A + (size_t)(m0 + lr) * 256 + lk;
    bf16x8 af[8];
    #pragma unroll
    for (int kk = 0; kk < 8; kk++) af[kk] = ldb8(Ap + kk * 32);

    __syncthreads();

    f32x4 acc[4] = {};
    #pragma unroll
    for (int kk = 0; kk < 8; kk++) {
        #pragma unroll
        for (int nt = 0; nt < 4; nt++) {
            int row = nt * 16 + lr;
            int g = (kk * 4 + hk) ^ ksw;
            bf16x8 bf = ldb8(Bt + (size_t)(row * 32 + g) * 8);
            acc[nt] = __builtin_amdgcn_mfma_f32_16x16x32_bf16(af[kk], bf, acc[nt], 0, 0, 0);
        }
    }
    int rbase = m0 + (hk << 2);
    #pragma unroll
    for (int nt = 0; nt < 4; nt++) {
        int col = n0 + nt * 16 + lr;
        #pragma unroll
        for (int j = 0; j < 4; j++) {
            int row = rbase + j;
            float v = acc[nt][j];
            if (MODE == 0) {
                v += bias[col];
                Cb[(size_t)row * 256 + col] = f2bf(v);
            } else {
                int b = col >> 10, p = col & 1023;
                size_t off = (size_t)b * (CH * HWPX) + (size_t)row * 1024 + p;
                v += bias[row];
                if (MODE == 1) Cb[off] = f2bf(v);
                else           Cf[off] = v + xres[off];
            }
        }
    }
}

// ---------------- K3: flash attention, 32x32 MFMA, swapped QK ----------------
// grid 256: bid -> xcd = bid&7 hosts batches 4x..4x+3. 4 waves x 32 q-rows.
// S^T = mfma(A=K, B=Q): lane owns q = q0+ (lane&31); 16 regs = 16 kv rows.
// PV:  O^T = mfma(A=V^T, B=P^T): P^T frags built in-register via shfl_xor(32).
__global__ __launch_bounds__(256, 1) void attn(
    const u16* __restrict__ Qt, const u16* __restrict__ Kt,
    const u16* __restrict__ Vc, u16* __restrict__ O)
{
    __shared__ __align__(16) u16 Kbuf[2][32 * 256];   // 2 x 16 KB, granule ^= kv&7
    __shared__ __align__(16) u16 Vbuf[2][256 * 32];   // 2 x 16 KB, granule ^= (c>>1)&3

    int tid = threadIdx.x;
    int lane = tid & 63, wave = tid >> 6;
    int bid = blockIdx.x;
    int b  = (bid & 7) * 4 + (bid >> 6);
    int qb = (bid >> 3) & 7;
    int q0 = qb * 128 + wave * 32;

    const u16* Qb = Qt + (size_t)b * (HWPX * CH);
    const u16* Kb = Kt + (size_t)b * (HWPX * CH);
    const u16* Vb = Vc + (size_t)b * (CH * HWPX);

    int lq = lane & 31, hi = lane >> 5;
    int kswz = lq & 7;
    int vswz = (lq >> 1) & 3;

    // staging source offsets (inverse-swizzled so LDS dest is linear)
    int koff[4], voff[4];
    #pragma unroll
    for (int i = 0; i < 4; i++) {
        int G = i * 256 + tid;
        int kr = G >> 5, kg = G & 31;
        koff[i] = kr * 256 + ((kg ^ (kr & 7)) << 3);
        int vr = G >> 2, vg = G & 3;
        voff[i] = vr * 1024 + ((vg ^ ((vr >> 1) & 3)) << 3);
    }

    // Q fragments (B-operand): qf[f] = Q[q0+lq][f*16 + hi*8 .. +7]
    bf16x8 qf[16];
    #pragma unroll
    for (int f = 0; f < 16; f++)
        qf[f] = ldb8(Qb + (size_t)(q0 + lq) * 256 + f * 16 + hi * 8);

    f32x16 oa[8] = {};          // O^T tiles: ct over c=32*ct.. ; 128 VGPRs
    float m_run = -1e30f, l_run = 0.f;

    // prologue: stage tile 0
    #pragma unroll
    for (int i = 0; i < 4; i++)
        gld_lds16(Kb + koff[i], &Kbuf[0][0] + (size_t)(i * 256 + wave * 64) * 8);
    #pragma unroll
    for (int i = 0; i < 4; i++)
        gld_lds16(Vb + voff[i], &Vbuf[0][0] + (size_t)(i * 256 + wave * 64) * 8);
    __syncthreads();

    for (int t = 0; t < 32; ++t) {
        int cur = t & 1;
        if (t < 31) {
            const u16* ks = Kb + (size_t)(t + 1) * (32 * 256);
            const u16* vs = Vb + (t + 1) * 32;
            #pragma unroll
            for (int i = 0; i < 4; i++)
                gld_lds16(ks + koff[i], &Kbuf[cur ^ 1][0] + (size_t)(i * 256 + wave * 64) * 8);
            #pragma unroll
            for (int i = 0; i < 4; i++)
                gld_lds16(vs + voff[i], &Vbuf[cur ^ 1][0] + (size_t)(i * 256 + wave * 64) * 8);
        }

        // ---- QK^T (S^T tile 32kv x 32q), two accumulators to shorten chain ----
        const u16* kb = Kbuf[cur];
        f32x16 s0 = {}, s1 = {};
        #pragma unroll
        for (int ff = 0; ff < 8; ff++) {
            bf16x8 ka0 = ldb8(kb + (size_t)lq * 256 + (((4 * ff + hi) ^ kswz) << 3));
            s0 = __builtin_amdgcn_mfma_f32_32x32x16_bf16(ka0, qf[2 * ff], s0, 0, 0, 0);
            bf16x8 ka1 = ldb8(kb + (size_t)lq * 256 + (((4 * ff + 2 + hi) ^ kswz) << 3));
            s1 = __builtin_amdgcn_mfma_f32_32x32x16_bf16(ka1, qf[2 * ff + 1], s1, 0, 0, 0);
        }
        float s[16];
        #pragma unroll
        for (int r = 0; r < 16; r++) s[r] = s0[r] + s1[r];

        // ---- lane-local defer-max softmax (log2 domain) ----
        float m01 = fmaxf(s[0], s[1]),   m23 = fmaxf(s[2], s[3]);
        float m45 = fmaxf(s[4], s[5]),   m67 = fmaxf(s[6], s[7]);
        float m89 = fmaxf(s[8], s[9]),   mab = fmaxf(s[10], s[11]);
        float mcd = fmaxf(s[12], s[13]), mef = fmaxf(s[14], s[15]);
        float mloc = fmaxf(fmaxf(fmaxf(m01, m23), fmaxf(m45, m67)),
                           fmaxf(fmaxf(m89, mab), fmaxf(mcd, mef)));
        if (!__all(mloc - m_run <= 4.f)) {          // rare: t==0 or max jumped
            float mo = fmaxf(mloc, __shfl_xor(mloc, 32));
            float mn = fmaxf(m_run, mo);
            float sc = exp2f(m_run - mn);
            m_run = mn;
            l_run *= sc;
            #pragma unroll
            for (int ct = 0; ct < 8; ct++) {
                #pragma unroll
                for (int r = 0; r < 16; r++) oa[ct][r] *= sc;
            }
        }
        float p[16];
        #pragma unroll
        for (int r = 0; r < 16; r++) p[r] = exp2f(s[r] - m_run);   // <= 2^4
        l_run += (((p[0]+p[1])+(p[2]+p[3]))+((p[4]+p[5])+(p[6]+p[7])))
               + (((p[8]+p[9])+(p[10]+p[11]))+((p[12]+p[13])+(p[14]+p[15])));

        // ---- build P^T B-fragments in-register ----
        u32 w0 = pk2(p[0],  p[1]),  w1 = pk2(p[2],  p[3]);
        u32 w2 = pk2(p[4],  p[5]),  w3 = pk2(p[6],  p[7]);
        u32 w4 = pk2(p[8],  p[9]),  w5 = pk2(p[10], p[11]);
        u32 w6 = pk2(p[12], p[13]), w7 = pk2(p[14], p[15]);
        u32 x0 = (u32)__shfl_xor((int)w0, 32), x1 = (u32)__shfl_xor((int)w1, 32);
        u32 x2 = (u32)__shfl_xor((int)w2, 32), x3 = (u32)__shfl_xor((int)w3, 32);
        u32 x4 = (u32)__shfl_xor((int)w4, 32), x5 = (u32)__shfl_xor((int)w5, 32);
        u32 x6 = (u32)__shfl_xor((int)w6, 32), x7 = (u32)__shfl_xor((int)w7, 32);
        u32x4 pf0 = { hi ? x2 : w0, hi ? x3 : w1, hi ? w2 : x0, hi ? w3 : x1 };
        u32x4 pf1 = { hi ? x6 : w4, hi ? x7 : w5, hi ? w6 : x4, hi ? w7 : x5 };
        bf16x8 pb0 = __builtin_bit_cast(bf16x8, pf0);
        bf16x8 pb1 = __builtin_bit_cast(bf16x8, pf1);

        // ---- PV: oa[ct] += V^T(c,kv) * P^T(kv,q) ----
        const u16* vb = Vbuf[cur];
        #pragma unroll
        for (int ct = 0; ct < 8; ct++) {
            int row = 32 * ct + lq;
            bf16x8 v0 = ldb8(vb + (size_t)row * 32 + (((hi)     ^ vswz) << 3));
            bf16x8 v1 = ldb8(vb + (size_t)row * 32 + (((2 + hi) ^ vswz) << 3));
            oa[ct] = __builtin_amdgcn_mfma_f32_32x32x16_bf16(v0, pb0, oa[ct], 0, 0, 0);
            oa[ct] = __builtin_amdgcn_mfma_f32_32x32x16_bf16(v1, pb1, oa[ct], 0, 0, 0);
        }
        __syncthreads();   // one barrier/step: next tiles staged, current reads done
    }

    float lt = l_run + __shfl_xor(l_run, 32);
    float rinv = 1.f / lt;
    u16* Ob = O + (size_t)b * (HWPX * CH) + (size_t)(q0 + lq) * 256;
    #pragma unroll
    for (int ct = 0; ct < 8; ct++) {
        #pragma unroll
        for (int rg = 0; rg < 4; rg++) {
            u16x4 st;
            #pragma unroll
            for (int v = 0; v < 4; v++) st[v] = f2bf(oa[ct][rg * 4 + v] * rinv);
            *(u16x4*)(Ob + 32 * ct + 8 * rg + 4 * hi) = st;
        }
    }
}

// ---------------- host launch ----------------
extern "C" void kernel_launch(void* const* d_in, const int* in_sizes, int n_in,
                              void* d_out, int out_size, void* d_ws, size_t ws_size,
                              hipStream_t stream)
{
    const float* x   = (const float*)d_in[0];
    const float* Wq  = (const float*)d_in[1];
    const float* bq  = (const float*)d_in[2];
    const float* Wk  = (const float*)d_in[3];
    const float* bk  = (const float*)d_in[4];
    const float* Wv  = (const float*)d_in[5];
    const float* bv  = (const float*)d_in[6];
    const float* Wo  = (const float*)d_in[7];
    const float* bo  = (const float*)d_in[8];
    const float* gqs = (const float*)d_in[9];
    const float* gqb = (const float*)d_in[10];
    const float* gks = (const float*)d_in[11];
    const float* gkb = (const float*)d_in[12];
    const float* gvs = (const float*)d_in[13];
    const float* gvb = (const float*)d_in[14];

    const size_t BIGB = (size_t)NB * HWPX * CH * 2;          // 16 MB per bf16 buffer
    const size_t WTB  = 4 * 65536 * 2;                       // 512 KB
    const size_t BIASB = 4 * 256 * 4;                        // 4 KB
    size_t need = 4 * BIGB + WTB + BIASB;
    if (ws_size < need) return;

    char* w = (char*)d_ws;
    u16*  Xh   = (u16*)(w);                    // [B][p][c]; reused as O after V proj
    u16*  Qt   = (u16*)(w + BIGB);
    u16*  Kt   = (u16*)(w + 2 * BIGB);
    u16*  Vc   = (u16*)(w + 3 * BIGB);
    u16*  Wt   = (u16*)(w + 4 * BIGB);
    float* bias = (float*)(w + 4 * BIGB + WTB);

    wprep<<<dim3(1024), dim3(256), 0, stream>>>(Wq, bq, gqs, gqb, Wk, bk, gks, gkb,
                                                Wv, bv, gvs, gvb, Wo, bo, Wt, bias);
    gn_kernel<<<dim3(1024), dim3(256), 0, stream>>>(x, Xh);

    gemm_nt<0><<<dim3(4, 512), dim3(256), 0, stream>>>(Xh, Wt,           bias,       Qt, nullptr, nullptr);
    gemm_nt<0><<<dim3(4, 512), dim3(256), 0, stream>>>(Xh, Wt + 65536,   bias + 256, Kt, nullptr, nullptr);
    gemm_nt<1><<<dim3(512, 4), dim3(256), 0, stream>>>(Wt + 131072, Xh,  bias + 512, Vc, nullptr, nullptr);
    attn<<<dim3(256), dim3(256), 0, stream>>>(Qt, Kt, Vc, Xh);
    gemm_nt<2><<<dim3(512, 4), dim3(256), 0, stream>>>(Wt + 196608, Xh,  bias + 768, nullptr, (float*)d_out, x);
}